// Round 11
// baseline (193.400 us; speedup 1.0000x reference)
//
#include <hip/hip_runtime.h>
#include <math.h>

#define B_ 2
#define T_ 2048
#define C_ 1024
#define H_ 16
#define D_ 64

typedef short short8 __attribute__((ext_vector_type(8)));
typedef float f32x4 __attribute__((ext_vector_type(4)));

#define LOG2E 1.44269504088896f

__device__ __forceinline__ unsigned short f2bf(float f) {
    unsigned int u = __float_as_uint(f);
    u += 0x7FFFu + ((u >> 16) & 1u);
    return (unsigned short)(u >> 16);
}
// round-half-up bf16 (2 VALU ops) — used for P only
__device__ __forceinline__ unsigned short f2bf_fast(float f) {
    return (unsigned short)((__float_as_uint(f) + 0x8000u) >> 16);
}

// ---------------------------------------------------------------------------
// W (H,C,D) fp32 -> Wt (H,D,C) bf16 slices of Wall^T. grid=(C/64, H, 3).
// (x / Wo casts are fused into qkv_big / out_big staging.)
// ---------------------------------------------------------------------------
__global__ __launch_bounds__(256) void transpose_w(
    const float* __restrict__ Wq, const float* __restrict__ Wk,
    const float* __restrict__ Wv, unsigned short* __restrict__ Wall)
{
    __shared__ float t[64][65];
    const int c0 = blockIdx.x * 64;
    const int h  = blockIdx.y;
    const int z  = blockIdx.z;
    const float* W = (z == 0) ? Wq : (z == 1) ? Wk : Wv;
    unsigned short* Wt = Wall + (size_t)z * H_ * D_ * C_;
    const int tid = threadIdx.x;
    const int r = tid >> 4, c4 = (tid & 15) * 4;
    #pragma unroll
    for (int p = 0; p < 4; p++) {
        int cl = r + p * 16;
        float4 v = *(const float4*)&W[((size_t)h * C_ + c0 + cl) * D_ + c4];
        t[cl][c4 + 0] = v.x; t[cl][c4 + 1] = v.y;
        t[cl][c4 + 2] = v.z; t[cl][c4 + 3] = v.w;
    }
    __syncthreads();
    #pragma unroll
    for (int p = 0; p < 4; p++) {
        int d = r + p * 16;
        ushort4 o;
        o.x = f2bf(t[c4 + 0][d]); o.y = f2bf(t[c4 + 1][d]);
        o.z = f2bf(t[c4 + 2][d]); o.w = f2bf(t[c4 + 3][d]);
        *(ushort4*)&Wt[((size_t)h * D_ + d) * C_ + c0 + c4] = o;
    }
}

// ---------------------------------------------------------------------------
// QKV GEMM, fused x-cast: X fp32 (4096x1024) x Wall^T bf16 (3072x1024),
// 128x128 tiles, register-prefetched; A-side converts fp32->bf16 during LDS
// staging (no separate cast pass). grid = (32, 24).
// z==0 -> Q (scaled 0.125*log2e), z==1 -> K, z==2 -> V^T (B,H,D,T) directly.
// ---------------------------------------------------------------------------
__global__ __launch_bounds__(256) void qkv_big(
    const float* __restrict__ X,
    const unsigned short* __restrict__ Wall,
    unsigned short* __restrict__ Qo,
    unsigned short* __restrict__ Ko,
    unsigned short* __restrict__ Vt)
{
    __shared__ unsigned short As[128][72];
    __shared__ unsigned short Bs[128][72];

    const int m0 = blockIdx.x * 128;
    const int n0 = blockIdx.y * 128;
    const int z  = n0 >> 10;
    const int tid = threadIdx.x;
    const int w = tid >> 6, lane = tid & 63, quad = lane >> 4, l16 = lane & 15;
    const int wm = w & 1, wn = w >> 1;
    const int lrow = tid >> 3, lcol = (tid & 7) * 8;

    f32x4 acc[4][4] = {};

    float4 arf[4][2];
    short8 br[4];
    #pragma unroll
    for (int p = 0; p < 4; p++) {
        int r = lrow + p * 32;
        arf[p][0] = *(const float4*)&X[(size_t)(m0 + r) * C_ + lcol];
        arf[p][1] = *(const float4*)&X[(size_t)(m0 + r) * C_ + lcol + 4];
        br[p] = *(const short8*)&Wall[(size_t)(n0 + r) * C_ + lcol];
    }

    for (int k0 = 0; k0 < C_; k0 += 64) {
        __syncthreads();
        #pragma unroll
        for (int p = 0; p < 4; p++) {
            int r = lrow + p * 32;
            ushort4 u0, u1;
            u0.x = f2bf(arf[p][0].x); u0.y = f2bf(arf[p][0].y);
            u0.z = f2bf(arf[p][0].z); u0.w = f2bf(arf[p][0].w);
            u1.x = f2bf(arf[p][1].x); u1.y = f2bf(arf[p][1].y);
            u1.z = f2bf(arf[p][1].z); u1.w = f2bf(arf[p][1].w);
            *(ushort4*)&As[r][lcol]     = u0;
            *(ushort4*)&As[r][lcol + 4] = u1;
            *(short8*)&Bs[r][lcol] = br[p];
        }
        __syncthreads();
        if (k0 + 64 < C_) {
            #pragma unroll
            for (int p = 0; p < 4; p++) {
                int r = lrow + p * 32;
                arf[p][0] = *(const float4*)&X[(size_t)(m0 + r) * C_ + k0 + 64 + lcol];
                arf[p][1] = *(const float4*)&X[(size_t)(m0 + r) * C_ + k0 + 64 + lcol + 4];
                br[p] = *(const short8*)&Wall[(size_t)(n0 + r) * C_ + k0 + 64 + lcol];
            }
        }
        #pragma unroll
        for (int ks = 0; ks < 2; ks++) {
            short8 af[4], bf[4];
            #pragma unroll
            for (int i = 0; i < 4; i++)
                af[i] = *(const short8*)&As[wm * 64 + i * 16 + l16][ks * 32 + quad * 8];
            #pragma unroll
            for (int j = 0; j < 4; j++)
                bf[j] = *(const short8*)&Bs[wn * 64 + j * 16 + l16][ks * 32 + quad * 8];
            #pragma unroll
            for (int i = 0; i < 4; i++)
                #pragma unroll
                for (int j = 0; j < 4; j++)
                    acc[i][j] = __builtin_amdgcn_mfma_f32_16x16x32_bf16(af[i], bf[j], acc[i][j], 0, 0, 0);
        }
    }

    if (z == 2) {
        // V^T epilogue: Vt[b,h,d,t], 4 consecutive t per (i,j) -> 8B stores
        #pragma unroll
        for (int j = 0; j < 4; j++) {
            const int n = n0 + wn * 64 + j * 16 + l16;
            const int h = (n >> 6) & 15, d = n & 63;
            #pragma unroll
            for (int i = 0; i < 4; i++) {
                const int m = m0 + wm * 64 + i * 16 + quad * 4;
                const int b = m >> 11, t = m & (T_ - 1);
                ushort4 pk;
                pk.x = f2bf(acc[i][j][0]);
                pk.y = f2bf(acc[i][j][1]);
                pk.z = f2bf(acc[i][j][2]);
                pk.w = f2bf(acc[i][j][3]);
                *(ushort4*)&Vt[(((size_t)b * H_ + h) * D_ + d) * T_ + t] = pk;
            }
        }
    } else {
        const float scale = (z == 0) ? 0.125f * LOG2E : 1.0f;
        unsigned short* O = (z == 0) ? Qo : Ko;
        #pragma unroll
        for (int j = 0; j < 4; j++) {
            const int n = n0 + wn * 64 + j * 16 + l16;
            const int h = (n >> 6) & 15, d = n & 63;
            #pragma unroll
            for (int i = 0; i < 4; i++)
                #pragma unroll
                for (int r = 0; r < 4; r++) {
                    const int m = m0 + wm * 64 + i * 16 + quad * 4 + r;
                    const int b = m >> 11, t = m & (T_ - 1);
                    O[(((size_t)b * H_ + h) * T_ + t) * D_ + d] = f2bf(acc[i][j][r] * scale);
                }
        }
    }
}

// ---------------------------------------------------------------------------
// Flash attention (causal), no-max exp2 softmax, intra-block K-split:
// 512 threads = two 4-wave groups; group g handles kb ≡ g (mod 2) with its
// own kst/vts/ps LDS (55.3 KB -> 2 blocks/CU = 16 waves/CU). Paired q-tiles
// (qb, 31-qb) keep every block at exactly 33 K-iters. Partial (O, l) are
// plain sums (no-max softmax) -> single LDS add to combine groups.
// grid = (16, H, B) = 512 blocks. [measured r8/r10: ~51 µs, occ ~35%]
// ---------------------------------------------------------------------------
__global__ __launch_bounds__(512, 4) void flash_mfma(
    const unsigned short* __restrict__ Q,
    const unsigned short* __restrict__ K,
    const unsigned short* __restrict__ Vt,   // (B,H,D,T)
    unsigned short* __restrict__ CC)         // (B,T,C)
{
    __shared__ unsigned short kst[2][64][72];   // K tile [s][d] per group
    __shared__ unsigned short vts[2][64][72];   // V^T tile [d][s] per group
    __shared__ unsigned short ps [2][64][72];   // P tile [q][s] per group

    const int pairid = blockIdx.x, h = blockIdx.y, b = blockIdx.z;
    const int tid = threadIdx.x;
    const int g  = tid >> 8;          // K-split group 0/1
    const int t2 = tid & 255;
    const int w = t2 >> 6, lane = t2 & 63, quad = lane >> 4, l16 = lane & 15;
    const int lrow = t2 >> 3, lcol = (t2 & 7) * 8;
    const size_t hb  = ((size_t)b * H_ + h) * T_;
    const size_t hbD = ((size_t)b * H_ + h) * D_;

    float* fob = (float*)&kst[0][0][0];  // combine buffer: 64 x 68 fp32
    float* flb = (float*)&ps[0][0][0];   // l combine buffer: 64 fp32

    for (int phase = 0; phase < 2; phase++) {
        const int qb = phase ? 31 - pairid : pairid;
        const int q0 = qb * 64;
        const int nkb = qb + 1;
        const int maxit = (nkb + 1) >> 1;

        short8 qf[2];
        #pragma unroll
        for (int ks = 0; ks < 2; ks++)
            qf[ks] = *(const short8*)&Q[(hb + q0 + w * 16 + l16) * D_ + ks * 32 + quad * 8];

        float l_part[4] = {0.f, 0.f, 0.f, 0.f};
        f32x4 o[4] = {};

        short8 kreg[2], vreg[2];
        {
            const int k0 = g * 64;   // in-bounds even if unused
            #pragma unroll
            for (int p = 0; p < 2; p++) {
                int r = lrow + p * 32;
                kreg[p] = *(const short8*)&K[(hb + k0 + r) * D_ + lcol];
                vreg[p] = *(const short8*)&Vt[(hbD + r) * T_ + k0 + lcol];
            }
        }

        for (int it = 0; it < maxit; it++) {
            const int kb = 2 * it + g;
            const bool act = (kb < nkb);
            __syncthreads();
            if (act) {
                #pragma unroll
                for (int p = 0; p < 2; p++) {
                    int r = lrow + p * 32;
                    *(short8*)&kst[g][r][lcol] = kreg[p];
                    *(short8*)&vts[g][r][lcol] = vreg[p];
                }
            }
            __syncthreads();
            if (kb + 2 < nkb) {
                const int k0n = (kb + 2) * 64;
                #pragma unroll
                for (int p = 0; p < 2; p++) {
                    int r = lrow + p * 32;
                    kreg[p] = *(const short8*)&K[(hb + k0n + r) * D_ + lcol];
                    vreg[p] = *(const short8*)&Vt[(hbD + r) * T_ + k0n + lcol];
                }
            }
            if (act) {
                // S = Q K^T
                f32x4 s[4] = {};
                #pragma unroll
                for (int ks = 0; ks < 2; ks++)
                    #pragma unroll
                    for (int ct = 0; ct < 4; ct++) {
                        short8 kf = *(const short8*)&kst[g][ct * 16 + l16][ks * 32 + quad * 8];
                        s[ct] = __builtin_amdgcn_mfma_f32_16x16x32_bf16(qf[ks], kf, s[ct], 0, 0, 0);
                    }

                if (kb == qb) {   // diagonal block
                    #pragma unroll
                    for (int ct = 0; ct < 4; ct++)
                        #pragma unroll
                        for (int r = 0; r < 4; r++) {
                            int qr = w * 16 + quad * 4 + r;
                            int kc = ct * 16 + l16;
                            if (kc > qr) s[ct][r] = -INFINITY;
                        }
                }

                // P = exp2(S); per-lane l partials; store P wave-private
                #pragma unroll
                for (int ct = 0; ct < 4; ct++)
                    #pragma unroll
                    for (int r = 0; r < 4; r++) {
                        float p = exp2f(s[ct][r]);
                        l_part[r] += p;
                        ps[g][w * 16 + quad * 4 + r][ct * 16 + l16] = f2bf_fast(p);
                    }

                // O += P V
                #pragma unroll
                for (int ks = 0; ks < 2; ks++) {
                    short8 pa = *(const short8*)&ps[g][w * 16 + l16][ks * 32 + quad * 8];
                    #pragma unroll
                    for (int ct = 0; ct < 4; ct++) {
                        short8 vf = *(const short8*)&vts[g][ct * 16 + l16][ks * 32 + quad * 8];
                        o[ct] = __builtin_amdgcn_mfma_f32_16x16x32_bf16(pa, vf, o[ct], 0, 0, 0);
                    }
                }
            }
        }

        // ---- combine groups (partials are plain sums) ----
        __syncthreads();
        if (g == 1) {
            #pragma unroll
            for (int r = 0; r < 4; r++) {
                float ls = l_part[r];
                ls += __shfl_xor(ls, 1);
                ls += __shfl_xor(ls, 2);
                ls += __shfl_xor(ls, 4);
                ls += __shfl_xor(ls, 8);
                if (l16 == 0) flb[w * 16 + quad * 4 + r] = ls;
                #pragma unroll
                for (int ct = 0; ct < 4; ct++)
                    fob[(w * 16 + quad * 4 + r) * 68 + ct * 16 + l16] = o[ct][r];
            }
        }
        __syncthreads();
        if (g == 0) {
            #pragma unroll
            for (int r = 0; r < 4; r++) {
                float ls = l_part[r];
                ls += __shfl_xor(ls, 1);
                ls += __shfl_xor(ls, 2);
                ls += __shfl_xor(ls, 4);
                ls += __shfl_xor(ls, 8);
                const int q = w * 16 + quad * 4 + r;
                ls += flb[q];
                const float invl = 1.0f / ls;
                const int t = q0 + q;
                #pragma unroll
                for (int ct = 0; ct < 4; ct++) {
                    float ov = o[ct][r] + fob[q * 68 + ct * 16 + l16];
                    CC[((size_t)b * T_ + t) * C_ + h * D_ + ct * 16 + l16] = f2bf(ov * invl);
                }
            }
        }
        __syncthreads();   // protect LDS reuse in next phase
    }
}

// ---------------------------------------------------------------------------
// Output projection, fused Wo-cast: out[m,n] = sum_c CC[m,c] * Wo[n,c],
// CC bf16, Wo fp32 (converted during staging). 128x128 tiles,
// register-prefetched. grid = (32, 8). fp32 output.
// ---------------------------------------------------------------------------
__global__ __launch_bounds__(256) void out_big(
    const unsigned short* __restrict__ X,
    const float* __restrict__ Wo,
    float* __restrict__ out)
{
    __shared__ unsigned short As[128][72];
    __shared__ unsigned short Bs[128][72];

    const int m0 = blockIdx.x * 128;
    const int n0 = blockIdx.y * 128;
    const int tid = threadIdx.x;
    const int w = tid >> 6, lane = tid & 63, quad = lane >> 4, l16 = lane & 15;
    const int wm = w & 1, wn = w >> 1;
    const int lrow = tid >> 3, lcol = (tid & 7) * 8;

    f32x4 acc[4][4] = {};

    short8 ar[4];
    float4 brf[4][2];
    #pragma unroll
    for (int p = 0; p < 4; p++) {
        int r = lrow + p * 32;
        ar[p] = *(const short8*)&X[(size_t)(m0 + r) * C_ + lcol];
        brf[p][0] = *(const float4*)&Wo[(size_t)(n0 + r) * C_ + lcol];
        brf[p][1] = *(const float4*)&Wo[(size_t)(n0 + r) * C_ + lcol + 4];
    }

    for (int k0 = 0; k0 < C_; k0 += 64) {
        __syncthreads();
        #pragma unroll
        for (int p = 0; p < 4; p++) {
            int r = lrow + p * 32;
            *(short8*)&As[r][lcol] = ar[p];
            ushort4 u0, u1;
            u0.x = f2bf(brf[p][0].x); u0.y = f2bf(brf[p][0].y);
            u0.z = f2bf(brf[p][0].z); u0.w = f2bf(brf[p][0].w);
            u1.x = f2bf(brf[p][1].x); u1.y = f2bf(brf[p][1].y);
            u1.z = f2bf(brf[p][1].z); u1.w = f2bf(brf[p][1].w);
            *(ushort4*)&Bs[r][lcol]     = u0;
            *(ushort4*)&Bs[r][lcol + 4] = u1;
        }
        __syncthreads();
        if (k0 + 64 < C_) {
            #pragma unroll
            for (int p = 0; p < 4; p++) {
                int r = lrow + p * 32;
                ar[p] = *(const short8*)&X[(size_t)(m0 + r) * C_ + k0 + 64 + lcol];
                brf[p][0] = *(const float4*)&Wo[(size_t)(n0 + r) * C_ + k0 + 64 + lcol];
                brf[p][1] = *(const float4*)&Wo[(size_t)(n0 + r) * C_ + k0 + 64 + lcol + 4];
            }
        }
        #pragma unroll
        for (int ks = 0; ks < 2; ks++) {
            short8 af[4], bf[4];
            #pragma unroll
            for (int i = 0; i < 4; i++)
                af[i] = *(const short8*)&As[wm * 64 + i * 16 + l16][ks * 32 + quad * 8];
            #pragma unroll
            for (int j = 0; j < 4; j++)
                bf[j] = *(const short8*)&Bs[wn * 64 + j * 16 + l16][ks * 32 + quad * 8];
            #pragma unroll
            for (int i = 0; i < 4; i++)
                #pragma unroll
                for (int j = 0; j < 4; j++)
                    acc[i][j] = __builtin_amdgcn_mfma_f32_16x16x32_bf16(af[i], bf[j], acc[i][j], 0, 0, 0);
        }
    }

    #pragma unroll
    for (int i = 0; i < 4; i++)
        #pragma unroll
        for (int j = 0; j < 4; j++)
            #pragma unroll
            for (int r = 0; r < 4; r++)
                out[(size_t)(m0 + wm * 64 + i * 16 + quad * 4 + r) * C_ + n0 + wn * 64 + j * 16 + l16] = acc[i][j][r];
}

extern "C" void kernel_launch(void* const* d_in, const int* in_sizes, int n_in,
                              void* d_out, int out_size, void* d_ws, size_t ws_size,
                              hipStream_t stream) {
    const float* x  = (const float*)d_in[0];
    const float* Wq = (const float*)d_in[1];
    const float* Wk = (const float*)d_in[2];
    const float* Wv = (const float*)d_in[3];
    const float* Wo = (const float*)d_in[4];
    float* out = (float*)d_out;

    const size_t nW = (size_t)H_ * C_ * D_;      // 1M per z
    const size_t nQ = (size_t)B_ * H_ * T_ * D_; // 4M
    unsigned short* Wall = (unsigned short*)d_ws;
    unsigned short* Qb   = Wall + 3 * nW;
    unsigned short* Kb   = Qb + nQ;
    unsigned short* Vtb  = Kb + nQ;
    unsigned short* CCb  = Vtb + nQ;   // total 19M ushorts = 38 MB

    transpose_w<<<dim3(C_ / 64, H_, 3), 256, 0, stream>>>(Wq, Wk, Wv, Wall);
    qkv_big<<<dim3(32, 24), 256, 0, stream>>>(x, Wall, Qb, Kb, Vtb);
    flash_mfma<<<dim3(16, H_, B_), 512, 0, stream>>>(Qb, Kb, Vtb, CCb);
    out_big<<<dim3(32, 8), 256, 0, stream>>>(CCb, Wo, out);
}

// Round 12
// 178.513 us; speedup vs baseline: 1.0834x; 1.0834x over previous
//
#include <hip/hip_runtime.h>
#include <math.h>

#define B_ 2
#define T_ 2048
#define C_ 1024
#define H_ 16
#define D_ 64

typedef short short8 __attribute__((ext_vector_type(8)));
typedef float f32x4 __attribute__((ext_vector_type(4)));

#define LOG2E 1.44269504088896f

__device__ __forceinline__ unsigned short f2bf(float f) {
    unsigned int u = __float_as_uint(f);
    u += 0x7FFFu + ((u >> 16) & 1u);
    return (unsigned short)(u >> 16);
}

#define NCAST 2560   // (4M + 1M) / 2048 cast blocks

// ---------------------------------------------------------------------------
// Fused prep: blocks [0,NCAST) cast x|Wo fp32->bf16 (8 elems/thread);
// blocks [NCAST, NCAST+768) transpose Wq/Wk/Wv (H,C,D)->(H,D,C) bf16 into
// Wall^T slices. [r10 verified]
// ---------------------------------------------------------------------------
__global__ __launch_bounds__(256) void prep_all(
    const float* __restrict__ x,  const float* __restrict__ Wq,
    const float* __restrict__ Wk, const float* __restrict__ Wv,
    const float* __restrict__ Wo,
    unsigned short* __restrict__ xb,   unsigned short* __restrict__ Wall,
    unsigned short* __restrict__ wob,  int nX, int nW)
{
    const int bid = blockIdx.x;
    const int tid = threadIdx.x;
    if (bid < NCAST) {
        int i = (bid * 256 + tid) * 8;
        const float* s;
        unsigned short* d;
        if (i < nX) { s = x + i; d = xb + i; }
        else {
            int j = i - nX;
            if (j >= nW) return;
            s = Wo + j; d = wob + j;
        }
        float4 a = *(const float4*)s;
        float4 b = *(const float4*)(s + 4);
        ushort4 o0, o1;
        o0.x = f2bf(a.x); o0.y = f2bf(a.y); o0.z = f2bf(a.z); o0.w = f2bf(a.w);
        o1.x = f2bf(b.x); o1.y = f2bf(b.y); o1.z = f2bf(b.z); o1.w = f2bf(b.w);
        *(ushort4*)d = o0;
        *(ushort4*)(d + 4) = o1;
        return;
    }
    // transpose path
    __shared__ float t[64][65];
    const int tb = bid - NCAST;          // 0..767
    const int c0 = (tb & 15) * 64;
    const int h  = (tb >> 4) & 15;
    const int z  = tb >> 8;
    const float* W = (z == 0) ? Wq : (z == 1) ? Wk : Wv;
    unsigned short* Wt = Wall + (size_t)z * H_ * D_ * C_;
    const int r = tid >> 4, c4 = (tid & 15) * 4;
    #pragma unroll
    for (int p = 0; p < 4; p++) {
        int cl = r + p * 16;
        float4 v = *(const float4*)&W[((size_t)h * C_ + c0 + cl) * D_ + c4];
        t[cl][c4 + 0] = v.x; t[cl][c4 + 1] = v.y;
        t[cl][c4 + 2] = v.z; t[cl][c4 + 3] = v.w;
    }
    __syncthreads();
    #pragma unroll
    for (int p = 0; p < 4; p++) {
        int d = r + p * 16;
        ushort4 o;
        o.x = f2bf(t[c4 + 0][d]); o.y = f2bf(t[c4 + 1][d]);
        o.z = f2bf(t[c4 + 2][d]); o.w = f2bf(t[c4 + 3][d]);
        *(ushort4*)&Wt[((size_t)h * D_ + d) * C_ + c0 + c4] = o;
    }
}

// ---------------------------------------------------------------------------
// QKV GEMM (r8/r10 register-prefetch structure): xb bf16 (4096x1024) x
// Wall^T bf16 (3072x1024), 128x128 tiles. grid = (32, 24).
// z==0 -> Q (scaled 0.125*log2e), z==1 -> K, z==2 -> V^T (B,H,D,T) directly.
// ---------------------------------------------------------------------------
__global__ __launch_bounds__(256) void qkv_big(
    const unsigned short* __restrict__ X,
    const unsigned short* __restrict__ Wall,
    unsigned short* __restrict__ Qo,
    unsigned short* __restrict__ Ko,
    unsigned short* __restrict__ Vt)
{
    __shared__ unsigned short As[128][72];
    __shared__ unsigned short Bs[128][72];

    const int m0 = blockIdx.x * 128;
    const int n0 = blockIdx.y * 128;
    const int z  = n0 >> 10;
    const int tid = threadIdx.x;
    const int w = tid >> 6, lane = tid & 63, quad = lane >> 4, l16 = lane & 15;
    const int wm = w & 1, wn = w >> 1;
    const int lrow = tid >> 3, lcol = (tid & 7) * 8;

    f32x4 acc[4][4] = {};

    short8 ar[4], br[4];
    #pragma unroll
    for (int p = 0; p < 4; p++) {
        int r = lrow + p * 32;
        ar[p] = *(const short8*)&X[(size_t)(m0 + r) * C_ + lcol];
        br[p] = *(const short8*)&Wall[(size_t)(n0 + r) * C_ + lcol];
    }

    for (int k0 = 0; k0 < C_; k0 += 64) {
        __syncthreads();
        #pragma unroll
        for (int p = 0; p < 4; p++) {
            int r = lrow + p * 32;
            *(short8*)&As[r][lcol] = ar[p];
            *(short8*)&Bs[r][lcol] = br[p];
        }
        __syncthreads();
        if (k0 + 64 < C_) {
            #pragma unroll
            for (int p = 0; p < 4; p++) {
                int r = lrow + p * 32;
                ar[p] = *(const short8*)&X[(size_t)(m0 + r) * C_ + k0 + 64 + lcol];
                br[p] = *(const short8*)&Wall[(size_t)(n0 + r) * C_ + k0 + 64 + lcol];
            }
        }
        #pragma unroll
        for (int ks = 0; ks < 2; ks++) {
            short8 af[4], bf[4];
            #pragma unroll
            for (int i = 0; i < 4; i++)
                af[i] = *(const short8*)&As[wm * 64 + i * 16 + l16][ks * 32 + quad * 8];
            #pragma unroll
            for (int j = 0; j < 4; j++)
                bf[j] = *(const short8*)&Bs[wn * 64 + j * 16 + l16][ks * 32 + quad * 8];
            #pragma unroll
            for (int i = 0; i < 4; i++)
                #pragma unroll
                for (int j = 0; j < 4; j++)
                    acc[i][j] = __builtin_amdgcn_mfma_f32_16x16x32_bf16(af[i], bf[j], acc[i][j], 0, 0, 0);
        }
    }

    if (z == 2) {
        // V^T epilogue: Vt[b,h,d,t], 4 consecutive t per (i,j) -> 8B stores
        #pragma unroll
        for (int j = 0; j < 4; j++) {
            const int n = n0 + wn * 64 + j * 16 + l16;
            const int h = (n >> 6) & 15, d = n & 63;
            #pragma unroll
            for (int i = 0; i < 4; i++) {
                const int m = m0 + wm * 64 + i * 16 + quad * 4;
                const int b = m >> 11, t = m & (T_ - 1);
                ushort4 pk;
                pk.x = f2bf(acc[i][j][0]);
                pk.y = f2bf(acc[i][j][1]);
                pk.z = f2bf(acc[i][j][2]);
                pk.w = f2bf(acc[i][j][3]);
                *(ushort4*)&Vt[(((size_t)b * H_ + h) * D_ + d) * T_ + t] = pk;
            }
        }
    } else {
        const float scale = (z == 0) ? 0.125f * LOG2E : 1.0f;
        unsigned short* O = (z == 0) ? Qo : Ko;
        #pragma unroll
        for (int j = 0; j < 4; j++) {
            const int n = n0 + wn * 64 + j * 16 + l16;
            const int h = (n >> 6) & 15, d = n & 63;
            #pragma unroll
            for (int i = 0; i < 4; i++)
                #pragma unroll
                for (int r = 0; r < 4; r++) {
                    const int m = m0 + wm * 64 + i * 16 + quad * 4 + r;
                    const int b = m >> 11, t = m & (T_ - 1);
                    O[(((size_t)b * H_ + h) * T_ + t) * D_ + d] = f2bf(acc[i][j][r] * scale);
                }
        }
    }
}

// ---------------------------------------------------------------------------
// Flash attention (causal), no-max exp2 softmax, intra-block K-split (r8),
// NEW: S^T variant — S' = K·Q^T (swapped MFMA operands, same LDS reads).
// Lane holds P at (s=quad*4+r, q=l16) -> P store becomes 4x ds_write_b64
// (v_perm pair packing) instead of 16x ds_write_b16; l is one scalar/lane.
// PV read (b128 A-frag) and O layout unchanged. grid = (16, H, B).
// ---------------------------------------------------------------------------
__global__ __launch_bounds__(512, 4) void flash_mfma(
    const unsigned short* __restrict__ Q,
    const unsigned short* __restrict__ K,
    const unsigned short* __restrict__ Vt,   // (B,H,D,T)
    unsigned short* __restrict__ CC)         // (B,T,C)
{
    __shared__ unsigned short kst[2][64][72];   // K tile [s][d] per group
    __shared__ unsigned short vts[2][64][72];   // V^T tile [d][s] per group
    __shared__ unsigned short ps [2][64][72];   // P tile [q][s] per group

    const int pairid = blockIdx.x, h = blockIdx.y, b = blockIdx.z;
    const int tid = threadIdx.x;
    const int g  = tid >> 8;          // K-split group 0/1
    const int t2 = tid & 255;
    const int w = t2 >> 6, lane = t2 & 63, quad = lane >> 4, l16 = lane & 15;
    const int lrow = t2 >> 3, lcol = (t2 & 7) * 8;
    const size_t hb  = ((size_t)b * H_ + h) * T_;
    const size_t hbD = ((size_t)b * H_ + h) * D_;

    float* fob = (float*)&kst[0][0][0];  // combine buffer: 64 x 68 fp32
    float* flb = (float*)&ps[0][0][0];   // l combine buffer: 64 fp32

    for (int phase = 0; phase < 2; phase++) {
        const int qb = phase ? 31 - pairid : pairid;
        const int q0 = qb * 64;
        const int nkb = qb + 1;
        const int maxit = (nkb + 1) >> 1;

        short8 qf[2];
        #pragma unroll
        for (int ks = 0; ks < 2; ks++)
            qf[ks] = *(const short8*)&Q[(hb + q0 + w * 16 + l16) * D_ + ks * 32 + quad * 8];

        float l_lane = 0.0f;   // l partial for q = w*16 + l16
        f32x4 o[4] = {};

        short8 kreg[2], vreg[2];
        {
            const int k0 = g * 64;   // in-bounds even if unused
            #pragma unroll
            for (int p = 0; p < 2; p++) {
                int r = lrow + p * 32;
                kreg[p] = *(const short8*)&K[(hb + k0 + r) * D_ + lcol];
                vreg[p] = *(const short8*)&Vt[(hbD + r) * T_ + k0 + lcol];
            }
        }

        for (int it = 0; it < maxit; it++) {
            const int kb = 2 * it + g;
            const bool act = (kb < nkb);
            __syncthreads();
            if (act) {
                #pragma unroll
                for (int p = 0; p < 2; p++) {
                    int r = lrow + p * 32;
                    *(short8*)&kst[g][r][lcol] = kreg[p];
                    *(short8*)&vts[g][r][lcol] = vreg[p];
                }
            }
            __syncthreads();
            if (kb + 2 < nkb) {
                const int k0n = (kb + 2) * 64;
                #pragma unroll
                for (int p = 0; p < 2; p++) {
                    int r = lrow + p * 32;
                    kreg[p] = *(const short8*)&K[(hb + k0n + r) * D_ + lcol];
                    vreg[p] = *(const short8*)&Vt[(hbD + r) * T_ + k0n + lcol];
                }
            }
            if (act) {
                // S' = K Q^T: lane holds s = ct*16 + quad*4 + r, q = w*16 + l16
                f32x4 s[4] = {};
                #pragma unroll
                for (int ks = 0; ks < 2; ks++)
                    #pragma unroll
                    for (int ct = 0; ct < 4; ct++) {
                        short8 kf = *(const short8*)&kst[g][ct * 16 + l16][ks * 32 + quad * 8];
                        s[ct] = __builtin_amdgcn_mfma_f32_16x16x32_bf16(kf, qf[ks], s[ct], 0, 0, 0);
                    }

                if (kb == qb) {   // diagonal block: mask s > q (local indices)
                    #pragma unroll
                    for (int ct = 0; ct < 4; ct++)
                        #pragma unroll
                        for (int r = 0; r < 4; r++)
                            if (ct * 16 + quad * 4 + r > w * 16 + l16) s[ct][r] = -INFINITY;
                }

                // P = exp2(S'); pack pairs to bf16 (round-half-up) -> b64 store
                #pragma unroll
                for (int ct = 0; ct < 4; ct++) {
                    float e0 = exp2f(s[ct][0]);
                    float e1 = exp2f(s[ct][1]);
                    float e2 = exp2f(s[ct][2]);
                    float e3 = exp2f(s[ct][3]);
                    l_lane += (e0 + e1) + (e2 + e3);
                    uint2 pk;
                    pk.x = __builtin_amdgcn_perm(
                        __float_as_uint(e1) + 0x8000u, __float_as_uint(e0) + 0x8000u, 0x07060302u);
                    pk.y = __builtin_amdgcn_perm(
                        __float_as_uint(e3) + 0x8000u, __float_as_uint(e2) + 0x8000u, 0x07060302u);
                    *(uint2*)&ps[g][w * 16 + l16][ct * 16 + quad * 4] = pk;
                }

                // O += P V (ps rows wave-private; A-frag b128 read unchanged)
                #pragma unroll
                for (int ks = 0; ks < 2; ks++) {
                    short8 pa = *(const short8*)&ps[g][w * 16 + l16][ks * 32 + quad * 8];
                    #pragma unroll
                    for (int ct = 0; ct < 4; ct++) {
                        short8 vf = *(const short8*)&vts[g][ct * 16 + l16][ks * 32 + quad * 8];
                        o[ct] = __builtin_amdgcn_mfma_f32_16x16x32_bf16(pa, vf, o[ct], 0, 0, 0);
                    }
                }
            }
        }

        // reduce l across quads (lanes sharing l16)
        l_lane += __shfl_xor(l_lane, 16);
        l_lane += __shfl_xor(l_lane, 32);

        // ---- combine groups (partials are plain sums) ----
        __syncthreads();
        if (g == 1) {
            if (lane < 16) flb[w * 16 + lane] = l_lane;
            #pragma unroll
            for (int ct = 0; ct < 4; ct++)
                #pragma unroll
                for (int r = 0; r < 4; r++)
                    fob[(w * 16 + quad * 4 + r) * 68 + ct * 16 + l16] = o[ct][r];
        }
        __syncthreads();
        if (g == 0) {
            float lt = l_lane + flb[w * 16 + l16];   // total l for q = w*16+l16
            if (lane < 16) flb[w * 16 + lane] = lt;  // transpose via wave-private LDS
            #pragma unroll
            for (int r = 0; r < 4; r++) {
                const int q = w * 16 + quad * 4 + r;
                const float invl = 1.0f / flb[q];
                const int t = q0 + q;
                #pragma unroll
                for (int ct = 0; ct < 4; ct++) {
                    float ov = o[ct][r] + fob[q * 68 + ct * 16 + l16];
                    CC[((size_t)b * T_ + t) * C_ + h * D_ + ct * 16 + l16] = f2bf(ov * invl);
                }
            }
        }
        __syncthreads();   // protect LDS reuse in next phase
    }
}

// ---------------------------------------------------------------------------
// Output projection (r8/r10 structure): out[m,n] = sum_c CC[m,c] * Wo[n,c],
// 128x128 tiles, register-prefetched. grid = (32, 8). fp32 output.
// ---------------------------------------------------------------------------
__global__ __launch_bounds__(256) void out_big(
    const unsigned short* __restrict__ X,
    const unsigned short* __restrict__ Wob,
    float* __restrict__ out)
{
    __shared__ unsigned short As[128][72];
    __shared__ unsigned short Bs[128][72];

    const int m0 = blockIdx.x * 128;
    const int n0 = blockIdx.y * 128;
    const int tid = threadIdx.x;
    const int w = tid >> 6, lane = tid & 63, quad = lane >> 4, l16 = lane & 15;
    const int wm = w & 1, wn = w >> 1;
    const int lrow = tid >> 3, lcol = (tid & 7) * 8;

    f32x4 acc[4][4] = {};

    short8 ar[4], br[4];
    #pragma unroll
    for (int p = 0; p < 4; p++) {
        int r = lrow + p * 32;
        ar[p] = *(const short8*)&X[(size_t)(m0 + r) * C_ + lcol];
        br[p] = *(const short8*)&Wob[(size_t)(n0 + r) * C_ + lcol];
    }

    for (int k0 = 0; k0 < C_; k0 += 64) {
        __syncthreads();
        #pragma unroll
        for (int p = 0; p < 4; p++) {
            int r = lrow + p * 32;
            *(short8*)&As[r][lcol] = ar[p];
            *(short8*)&Bs[r][lcol] = br[p];
        }
        __syncthreads();
        if (k0 + 64 < C_) {
            #pragma unroll
            for (int p = 0; p < 4; p++) {
                int r = lrow + p * 32;
                ar[p] = *(const short8*)&X[(size_t)(m0 + r) * C_ + k0 + 64 + lcol];
                br[p] = *(const short8*)&Wob[(size_t)(n0 + r) * C_ + k0 + 64 + lcol];
            }
        }
        #pragma unroll
        for (int ks = 0; ks < 2; ks++) {
            short8 af[4], bf[4];
            #pragma unroll
            for (int i = 0; i < 4; i++)
                af[i] = *(const short8*)&As[wm * 64 + i * 16 + l16][ks * 32 + quad * 8];
            #pragma unroll
            for (int j = 0; j < 4; j++)
                bf[j] = *(const short8*)&Bs[wn * 64 + j * 16 + l16][ks * 32 + quad * 8];
            #pragma unroll
            for (int i = 0; i < 4; i++)
                #pragma unroll
                for (int j = 0; j < 4; j++)
                    acc[i][j] = __builtin_amdgcn_mfma_f32_16x16x32_bf16(af[i], bf[j], acc[i][j], 0, 0, 0);
        }
    }

    #pragma unroll
    for (int i = 0; i < 4; i++)
        #pragma unroll
        for (int j = 0; j < 4; j++)
            #pragma unroll
            for (int r = 0; r < 4; r++)
                out[(size_t)(m0 + wm * 64 + i * 16 + quad * 4 + r) * C_ + n0 + wn * 64 + j * 16 + l16] = acc[i][j][r];
}

extern "C" void kernel_launch(void* const* d_in, const int* in_sizes, int n_in,
                              void* d_out, int out_size, void* d_ws, size_t ws_size,
                              hipStream_t stream) {
    const float* x  = (const float*)d_in[0];
    const float* Wq = (const float*)d_in[1];
    const float* Wk = (const float*)d_in[2];
    const float* Wv = (const float*)d_in[3];
    const float* Wo = (const float*)d_in[4];
    float* out = (float*)d_out;

    const size_t nX = (size_t)B_ * T_ * C_;      // 4M
    const size_t nW = (size_t)H_ * C_ * D_;      // 1M per z
    const size_t nQ = (size_t)B_ * H_ * T_ * D_; // 4M
    unsigned short* xb   = (unsigned short*)d_ws;
    unsigned short* Wall = xb + nX;
    unsigned short* Wob  = Wall + 3 * nW;
    unsigned short* Qb   = Wob + nW;
    unsigned short* Kb   = Qb + nQ;
    unsigned short* Vtb  = Kb + nQ;
    unsigned short* CCb  = Vtb + nQ;   // total 24M ushorts = 48 MB

    prep_all<<<dim3(NCAST + 768), 256, 0, stream>>>(
        x, Wq, Wk, Wv, Wo, xb, Wall, Wob, (int)nX, (int)nW);
    qkv_big<<<dim3(32, 24), 256, 0, stream>>>(xb, Wall, Qb, Kb, Vtb);
    flash_mfma<<<dim3(16, H_, B_), 512, 0, stream>>>(Qb, Kb, Vtb, CCb);
    out_big<<<dim3(32, 8), 256, 0, stream>>>(CCb, Wob, out);
}